// Round 2
// baseline (115.572 us; speedup 1.0000x reference)
//
#include <hip/hip_runtime.h>
#include <cstdint>

#define DD 24
#define AA 13824          // 24*24*24
#define NF4 3456          // AA/4
#define BLOCK 1024
#define TOPK 60           // output rows per batch
#define NSEL 20           // only the first NMS_TOPK=20 valid candidates can ever be kept
#define THRESH 0.15f
#define NMS_THR 0.05f
#define NBINS 1024
#define BUFCAP 2048
#define T1BASE 1008       // (u>>20) for 0.5f: tier-1 histograms only values >= 0.5

__device__ __forceinline__ unsigned skey(float f) {
    unsigned u = __float_as_uint(f);
    return (u & 0x80000000u) ? ~u : (u | 0x80000000u);
}

// bin in [0,NBINS) or -1 if excluded. tier is a compile-time constant at call sites.
// tier 1: positives >= 0.5 (always sufficient for N(0,1) bench data; verified via scan total)
// tier 2: all positives (coarser by 1 bit)    -- fallback, never taken on bench
// tier 3: all values via 10-bit sortable key  -- fallback of the fallback
__device__ __forceinline__ int binof(float f, int tier) {
    const unsigned u = __float_as_uint(f);
    if (tier == 1) {
        if (u & 0x80000000u) return -1;
        int t = (int)(u >> 20) - T1BASE;
        if (t < 0) return -1;
        return t > (NBINS - 1) ? (NBINS - 1) : t;
    } else if (tier == 2) {
        if (u & 0x80000000u) return -1;
        return (int)(u >> 21);           // u <= 0x7fffffff -> [0,1024)
    }
    return (int)(skey(f) >> 22);         // [0,1024)
}

__global__ __launch_bounds__(BLOCK, 4) void detpost(
    const float* __restrict__ cls,
    const float* __restrict__ shp,
    const float* __restrict__ off,
    float* __restrict__ out)
{
    __shared__ int   s_hist[NBINS];      // NBINS == BLOCK: one clear-store per thread
    __shared__ int   s_cnt;
    __shared__ int   s_bt;
    __shared__ int   s_done;
    __shared__ float s_bufv[BUFCAP];
    __shared__ int   s_bufi[BUFCAP];
    __shared__ float s_topv[NSEL];
    __shared__ int   s_topi[NSEL];

    const int b   = blockIdx.x;
    const int tid = threadIdx.x;

    // ---- issue global loads first so HBM latency overlaps the LDS clear ----
    const float4* cls4 = (const float4*)(cls + (size_t)b * AA);
    const bool has3 = (tid + 3072) < NF4;    // threads 0..383
    float4 r0 = cls4[tid];
    float4 r1 = cls4[tid + 1024];
    float4 r2 = cls4[tid + 2048];
    float4 r3 = has3 ? cls4[tid + 3072] : make_float4(0.f, 0.f, 0.f, 0.f);

    s_hist[tid] = 0;
    if (tid == 0) s_cnt = 0;
    __syncthreads();

    // ---- tiered histogram + one-wave pivot scan ----
    int tier = 1;
    for (;; ++tier) {
        #define HB(v, g, T) { if (g) { const int bn = binof((v), (T)); \
                               if (bn >= 0) atomicAdd(&s_hist[bn], 1); } }
        #define HPASS(T) { HB(r0.x, true, T) HB(r0.y, true, T) HB(r0.z, true, T) HB(r0.w, true, T) \
                           HB(r1.x, true, T) HB(r1.y, true, T) HB(r1.z, true, T) HB(r1.w, true, T) \
                           HB(r2.x, true, T) HB(r2.y, true, T) HB(r2.z, true, T) HB(r2.w, true, T) \
                           HB(r3.x, has3, T) HB(r3.y, has3, T) HB(r3.z, has3, T) HB(r3.w, has3, T) }
        if (tier == 1)      HPASS(1)
        else if (tier == 2) HPASS(2)
        else                HPASS(3)
        #undef HPASS
        #undef HB
        __syncthreads();

        if (tid < 64) {
            const int lane = tid;
            int part = 0;
            #pragma unroll
            for (int i = 0; i < 16; ++i) part += s_hist[lane * 16 + i];
            // reverse inclusive wave scan: x_l = sum of part over lanes >= l
            int x = part;
            #pragma unroll
            for (int d = 1; d < 64; d <<= 1) {
                int y = __shfl_down(x, d, 64);
                if (lane + d < 64) x += y;
            }
            const unsigned long long ball = __ballot(x >= NSEL);   // bit0 set iff total >= NSEL
            if (ball) {
                const int seg    = 63 - __clzll((long long)ball);  // largest seg with suffix >= NSEL
                const int Safter = (seg < 63) ? __shfl(x, seg + 1, 64) : 0;
                int c = (lane < 16) ? s_hist[seg * 16 + lane] : 0;
                int sx = c;                                        // reverse scan within segment
                #pragma unroll
                for (int d = 1; d < 16; d <<= 1) {
                    int y = __shfl_down(sx, d, 64);
                    if (lane + d < 16) sx += y;
                }
                const unsigned long long b2 = __ballot((lane < 16) && (sx + Safter >= NSEL));
                if (lane == 0) { s_bt = seg * 16 + (63 - __clzll((long long)b2)); s_done = 1; }
            } else if (lane == 0) s_done = 0;
        }
        __syncthreads();
        if (s_done) break;                 // tier 3 always succeeds (13824 >= NSEL)
        s_hist[tid] = 0;
        __syncthreads();
    }
    const int bt = s_bt;

    // ---- collect candidates from registers ----
    {
        const int b0 = 4 * tid, b1 = 4 * (tid + 1024), b2 = 4 * (tid + 2048), b3 = 4 * (tid + 3072);
        #define CB(v, e, g, T) { if (g) { if (binof((v), (T)) >= bt) { \
            int pos = atomicAdd(&s_cnt, 1); \
            if (pos < BUFCAP) { s_bufv[pos] = (v); s_bufi[pos] = (e); } } } }
        #define CPASS(T) { CB(r0.x, b0+0, true, T) CB(r0.y, b0+1, true, T) CB(r0.z, b0+2, true, T) CB(r0.w, b0+3, true, T) \
                           CB(r1.x, b1+0, true, T) CB(r1.y, b1+1, true, T) CB(r1.z, b1+2, true, T) CB(r1.w, b1+3, true, T) \
                           CB(r2.x, b2+0, true, T) CB(r2.y, b2+1, true, T) CB(r2.z, b2+2, true, T) CB(r2.w, b2+3, true, T) \
                           CB(r3.x, b3+0, has3, T) CB(r3.y, b3+1, has3, T) CB(r3.z, b3+2, has3, T) CB(r3.w, b3+3, has3, T) }
        if (tier == 1)      CPASS(1)
        else if (tier == 2) CPASS(2)
        else                CPASS(3)
        #undef CPASS
        #undef CB
    }
    __syncthreads();
    int C = s_cnt; if (C > BUFCAP) C = BUFCAP;

    // ---- exact top-NSEL by rank counting (desc value, tie: lower index first) ----
    for (int j = tid; j < C; j += BLOCK) {
        const float vj = s_bufv[j];
        const int   ij = s_bufi[j];
        int r = 0;
        for (int k = 0; k < C; ++k) {
            const float vk = s_bufv[k];
            const int   ik = s_bufi[k];
            r += (int)((vk > vj) || (vk == vj && ik < ij));
        }
        if (r < NSEL) { s_topv[r] = vj; s_topi[r] = ij; }
    }
    __syncthreads();

    // ---- wave 0 finishes alone: decode, IoU, NMS, output — all in registers ----
    if (tid >= 64) return;
    const int lane = tid;

    float score = -2.0f;
    float cz = 0.f, cy = 0.f, cx = 0.f, ez = 0.f, ey = 0.f, ex = 0.f;
    float loz = 0.f, loy = 0.f, lox = 0.f, hiz = 0.f, hiy = 0.f, hix = 0.f, vol = 0.f;
    if (lane < NSEL) {
        const float v = s_topv[lane];
        const int   a = s_topi[lane];
        score = 1.0f / (1.0f + expf(-v));
        const int z  = a / (DD * DD);
        const int y  = (a / DD) % DD;
        const int xg = a % DD;
        const size_t base3 = (size_t)b * 3 * AA;
        const float o0 = off[base3 + 0 * AA + a];
        const float o1 = off[base3 + 1 * AA + a];
        const float o2 = off[base3 + 2 * AA + a];
        const float s0 = shp[base3 + 0 * AA + a];
        const float s1 = shp[base3 + 1 * AA + a];
        const float s2 = shp[base3 + 2 * AA + a];
        cz = ((float)z  + o0) * 4.0f;
        cy = ((float)y  + o1) * 4.0f;
        cx = ((float)xg + o2) * 4.0f;
        ez = 2.0f * s0; ey = 2.0f * s1; ex = 2.0f * s2;
        // mirror reference fp op order exactly
        loz = cz - ez * 0.5f;  hiz = cz + ez * 0.5f;
        loy = cy - ey * 0.5f;  hiy = cy + ey * 0.5f;
        lox = cx - ex * 0.5f;  hix = cx + ex * 0.5f;
        vol = (ez * ey) * ex;
    }

    // candidate mask: valid entries of the top-NSEL (rank<NMS_TOPK automatic — see NSEL note)
    const unsigned cand =
        (unsigned)__ballot((lane < NSEL) && (score > THRESH)) & ((1u << NSEL) - 1u);

    // per-lane IoU suppression mask via shuffles (shuffles outside divergence)
    unsigned m = 0u;
    for (int j = 0; j < NSEL; ++j) {
        const float ljz = __shfl(loz, j, 64), hjz = __shfl(hiz, j, 64);
        const float ljy = __shfl(loy, j, 64), hjy = __shfl(hiy, j, 64);
        const float ljx = __shfl(lox, j, 64), hjx = __shfl(hix, j, 64);
        const float vj  = __shfl(vol, j, 64);
        if ((lane < NSEL) && (j != lane)) {
            const float tz = fmaxf(fminf(hiz, hjz) - fmaxf(loz, ljz), 0.0f);
            const float ty = fmaxf(fminf(hiy, hjy) - fmaxf(loy, ljy), 0.0f);
            const float tx = fmaxf(fminf(hix, hjx) - fmaxf(lox, ljx), 0.0f);
            const float inter = (tz * ty) * tx;
            const float uni   = (vol + vj) - inter;
            const float iou   = inter / fmaxf(uni, 1e-8f);
            if (iou > NMS_THR) m |= (1u << j);
        }
    }

    // serial greedy NMS — uniform across the wave, pure register bit ops
    unsigned kept = 0u, supp = 0u;
    #pragma unroll 1
    for (int i = 0; i < NSEL; ++i) {
        const unsigned mi  = (unsigned)__shfl((int)m, i, 64);  // all lanes participate
        const unsigned bit = 1u << i;
        if ((cand & bit) && !(supp & bit)) { kept |= bit; supp |= mi; }
    }

    // ---- output ----
    const int K = __popc(kept);
    float* ob = out + (size_t)b * (TOPK * 8);
    if ((lane < NSEL) && ((kept >> lane) & 1u)) {
        const int r = __popc(kept & ((1u << lane) - 1u));
        float4* row = (float4*)(ob + r * 8);
        row[0] = make_float4(1.0f, score, cz, cy);
        row[1] = make_float4(cx, ez, ey, ex);
    }
    const int n4 = (TOPK - K) * 2;               // float4s of -1 fill
    float4* fb = (float4*)(ob + K * 8);
    const float4 neg = make_float4(-1.f, -1.f, -1.f, -1.f);
    for (int i = lane; i < n4; i += 64) fb[i] = neg;
}

extern "C" void kernel_launch(void* const* d_in, const int* in_sizes, int n_in,
                              void* d_out, int out_size, void* d_ws, size_t ws_size,
                              hipStream_t stream) {
    (void)n_in; (void)out_size; (void)d_ws; (void)ws_size;
    const float* cls = (const float*)d_in[0];
    const float* shp = (const float*)d_in[1];
    const float* off = (const float*)d_in[2];
    float* out = (float*)d_out;
    const int B = in_sizes[0] / AA;   // 256
    detpost<<<B, BLOCK, 0, stream>>>(cls, shp, off, out);
}

// Round 3
// 114.452 us; speedup vs baseline: 1.0098x; 1.0098x over previous
//
#include <hip/hip_runtime.h>
#include <cstdint>

#define DD 24
#define AA 13824          // 24*24*24
#define NF4 3456          // AA/4
#define BLOCK 1024
#define TOPK 60           // output rows per batch
#define NSEL 20           // only the first NMS_TOPK=20 valid candidates can ever be kept:
                          // valid scores (>THRESH) are strictly greater than invalid ones,
                          // so top-20-by-value contains the whole cand set of the reference.
#define THRESH 0.15f
#define NMS_THR 0.05f
#define NBINS 4096
#define NPAD 4352         // 4096 + 4096/16: stride-17 padding kills the 32-way scan conflict
#define BUFCAP 2048

__device__ __forceinline__ unsigned skey(float f) {
    unsigned u = __float_as_uint(f);
    return (u & 0x80000000u) ? ~u : (u | 0x80000000u);
}
// padded histogram slot for bin b (stride 17 per 16-bin segment)
__device__ __forceinline__ int hslot(int b) { return b + (b >> 4); }

__global__ __launch_bounds__(BLOCK, 4) void detpost(
    const float* __restrict__ cls,
    const float* __restrict__ shp,
    const float* __restrict__ off,
    float* __restrict__ out)
{
    __shared__ int      s_hist[NPAD];
    __shared__ int      s_S[257];
    __shared__ int      s_wsum[4];
    __shared__ int      s_seg;
    __shared__ int      s_bt;
    __shared__ int      s_cnt;
    __shared__ float    s_bufv[BUFCAP];
    __shared__ int      s_bufi[BUFCAP];
    __shared__ float    s_topv[NSEL];
    __shared__ int      s_topi[NSEL];
    __shared__ float    s_lo[3][NSEL], s_hi[3][NSEL], s_vol[NSEL];
    __shared__ unsigned s_m[NSEL];           // 20-bit suppression masks
    __shared__ unsigned s_keptmask;

    const int b   = blockIdx.x;
    const int tid = threadIdx.x;

    // ---- issue global loads first so HBM latency overlaps the LDS clear ----
    const float4* cls4 = (const float4*)(cls + (size_t)b * AA);
    const bool has3 = (tid + 3072) < NF4;    // threads 0..383
    float4 r0 = cls4[tid];
    float4 r1 = cls4[tid + 1024];
    float4 r2 = cls4[tid + 2048];
    float4 r3 = has3 ? cls4[tid + 3072] : make_float4(0.f, 0.f, 0.f, 0.f);

    for (int i = tid; i < NPAD; i += BLOCK) s_hist[i] = 0;
    if (tid == 0) { s_cnt = 0; s_seg = 0; s_S[256] = 0; }
    __syncthreads();

    // ---- Pass 1: histogram of top-12-bit sortable keys (spread, unconditional) ----
    atomicAdd(&s_hist[hslot(skey(r0.x) >> 20)], 1);
    atomicAdd(&s_hist[hslot(skey(r0.y) >> 20)], 1);
    atomicAdd(&s_hist[hslot(skey(r0.z) >> 20)], 1);
    atomicAdd(&s_hist[hslot(skey(r0.w) >> 20)], 1);
    atomicAdd(&s_hist[hslot(skey(r1.x) >> 20)], 1);
    atomicAdd(&s_hist[hslot(skey(r1.y) >> 20)], 1);
    atomicAdd(&s_hist[hslot(skey(r1.z) >> 20)], 1);
    atomicAdd(&s_hist[hslot(skey(r1.w) >> 20)], 1);
    atomicAdd(&s_hist[hslot(skey(r2.x) >> 20)], 1);
    atomicAdd(&s_hist[hslot(skey(r2.y) >> 20)], 1);
    atomicAdd(&s_hist[hslot(skey(r2.z) >> 20)], 1);
    atomicAdd(&s_hist[hslot(skey(r2.w) >> 20)], 1);
    if (has3) {
        atomicAdd(&s_hist[hslot(skey(r3.x) >> 20)], 1);
        atomicAdd(&s_hist[hslot(skey(r3.y) >> 20)], 1);
        atomicAdd(&s_hist[hslot(skey(r3.z) >> 20)], 1);
        atomicAdd(&s_hist[hslot(skey(r3.w) >> 20)], 1);
    }
    __syncthreads();

    // ---- Pivot scan phase A: 256 threads, per-segment sums + wave scans ----
    if (tid < 256) {
        int part = 0;
        #pragma unroll
        for (int i = 0; i < 16; ++i) part += s_hist[tid * 17 + i];   // stride-17: conflict-free
        const int lane = tid & 63;
        int x = part;
        #pragma unroll
        for (int d2 = 1; d2 < 64; d2 <<= 1) {
            int y = __shfl_up(x, d2, 64);
            if (lane >= d2) x += y;
        }
        if (lane == 63) s_wsum[tid >> 6] = x;
        s_S[tid] = part;                       // stash segment count
        s_bufv[tid] = __int_as_float(x);       // stash inclusive wave-scan
    }
    __syncthreads();

    // ---- Pivot scan phase B: cross-wave combine -> suffix sums, pick segment ----
    if (tid < 256) {
        const int wv = tid >> 6;
        const int part = s_S[tid];
        const int x = __float_as_int(s_bufv[tid]);
        int offp = 0, tot = 0;
        #pragma unroll
        for (int wq = 0; wq < 4; ++wq) {
            int s = s_wsum[wq];
            tot += s;
            if (wq < wv) offp += s;
        }
        const int Pincl = x + offp;
        const int S = tot - Pincl + part;   // suffix sum over segments >= tid
        s_S[tid] = S;
        if (S >= NSEL) atomicMax(&s_seg, tid);
    }
    __syncthreads();

    // ---- Pivot refine: wave 0, 16 parallel reads + 4-hop suffix scan + ballot ----
    if (tid < 64) {
        const int seg    = s_seg;
        const int Safter = s_S[seg + 1];                 // s_S[256]==0 covers seg==255
        int sx = (tid < 16) ? s_hist[seg * 17 + tid] : 0;
        #pragma unroll
        for (int d = 1; d < 16; d <<= 1) {
            int y = __shfl_down(sx, d, 64);
            if (tid + d < 16) sx += y;
        }
        const unsigned long long b2 = __ballot((tid < 16) && (sx + Safter >= NSEL));
        if (tid == 0) s_bt = seg * 16 + (63 - __clzll((long long)b2));  // largest qualifying bin
    }
    __syncthreads();
    const unsigned bt = (unsigned)s_bt;

    // ---- Pass 2: collect candidates from registers ----
    {
        const int b0 = 4 * tid, b1 = 4 * (tid + 1024), b2 = 4 * (tid + 2048), b3 = 4 * (tid + 3072);
        #define COLL(v, e) if ((skey(v) >> 20) >= bt) { \
            int pos = atomicAdd(&s_cnt, 1); \
            if (pos < BUFCAP) { s_bufv[pos] = (v); s_bufi[pos] = (e); } }
        COLL(r0.x, b0 + 0) COLL(r0.y, b0 + 1) COLL(r0.z, b0 + 2) COLL(r0.w, b0 + 3)
        COLL(r1.x, b1 + 0) COLL(r1.y, b1 + 1) COLL(r1.z, b1 + 2) COLL(r1.w, b1 + 3)
        COLL(r2.x, b2 + 0) COLL(r2.y, b2 + 1) COLL(r2.z, b2 + 2) COLL(r2.w, b2 + 3)
        if (has3) { COLL(r3.x, b3 + 0) COLL(r3.y, b3 + 1) COLL(r3.z, b3 + 2) COLL(r3.w, b3 + 3) }
        #undef COLL
    }
    __syncthreads();
    int C = s_cnt; if (C > BUFCAP) C = BUFCAP;

    // ---- Exact top-NSEL by rank counting (desc value, tie: lower index first) ----
    for (int j = tid; j < C; j += BLOCK) {
        const float vj = s_bufv[j];
        const int   ij = s_bufi[j];
        int r = 0;
        for (int k = 0; k < C; ++k) {
            const float vk = s_bufv[k];
            const int   ik = s_bufi[k];
            r += (int)((vk > vj) || (vk == vj && ik < ij));
        }
        if (r < NSEL) { s_topv[r] = vj; s_topi[r] = ij; }
    }
    __syncthreads();

    // ---- Decode boxes (lanes 0..19 of wave 0; det row stays in registers) ----
    float score = -2.0f;
    float cz = 0.f, cy = 0.f, cx = 0.f, ez = 0.f, ey = 0.f, ex = 0.f;
    unsigned cand = 0u;
    if (tid < 64) {
        if (tid < NSEL) {
            s_m[tid] = 0u;
            const float v = s_topv[tid];
            const int   a = s_topi[tid];
            score = 1.0f / (1.0f + expf(-v));
            const int z  = a / (DD * DD);
            const int y  = (a / DD) % DD;
            const int xg = a % DD;
            const size_t base3 = (size_t)b * 3 * AA;
            const float o0 = off[base3 + 0 * AA + a];
            const float o1 = off[base3 + 1 * AA + a];
            const float o2 = off[base3 + 2 * AA + a];
            const float s0 = shp[base3 + 0 * AA + a];
            const float s1 = shp[base3 + 1 * AA + a];
            const float s2 = shp[base3 + 2 * AA + a];
            cz = ((float)z  + o0) * 4.0f;
            cy = ((float)y  + o1) * 4.0f;
            cx = ((float)xg + o2) * 4.0f;
            ez = 2.0f * s0; ey = 2.0f * s1; ex = 2.0f * s2;
            // mirror reference fp op order exactly
            s_lo[0][tid] = cz - ez * 0.5f;  s_hi[0][tid] = cz + ez * 0.5f;
            s_lo[1][tid] = cy - ey * 0.5f;  s_hi[1][tid] = cy + ey * 0.5f;
            s_lo[2][tid] = cx - ex * 0.5f;  s_hi[2][tid] = cx + ex * 0.5f;
            s_vol[tid]   = (ez * ey) * ex;
        }
        // candidate mask: all valid (>THRESH) entries rank ahead of invalid ones,
        // so rank<NMS_TOPK is automatic within the top-NSEL. Register survives barriers.
        cand = (unsigned)__ballot((tid < NSEL) && (score > THRESH)) & ((1u << NSEL) - 1u);
    }
    __syncthreads();

    // ---- Parallel IoU suppression masks (400 pairs across 400 threads) ----
    if (tid < NSEL * NSEL) {
        const int i = tid / NSEL, j = tid - i * NSEL;
        if (i != j) {
            const float tz = fmaxf(fminf(s_hi[0][i], s_hi[0][j]) - fmaxf(s_lo[0][i], s_lo[0][j]), 0.0f);
            const float ty = fmaxf(fminf(s_hi[1][i], s_hi[1][j]) - fmaxf(s_lo[1][i], s_lo[1][j]), 0.0f);
            const float tx = fmaxf(fminf(s_hi[2][i], s_hi[2][j]) - fmaxf(s_lo[2][i], s_lo[2][j]), 0.0f);
            const float inter = (tz * ty) * tx;
            const float uni = (s_vol[i] + s_vol[j]) - inter;
            const float iou = inter / fmaxf(uni, 1e-8f);
            if (iou > NMS_THR) atomicOr(&s_m[i], 1u << j);
        }
    }
    __syncthreads();

    // ---- Serial greedy NMS: masks preloaded into registers (static indices) ----
    if (tid == 0) {
        unsigned mv[NSEL];
        #pragma unroll
        for (int i = 0; i < NSEL; ++i) mv[i] = s_m[i];   // independent loads, pipelined
        unsigned kept = 0u, supp = 0u;
        #pragma unroll
        for (int i = 0; i < NSEL; ++i) {
            const unsigned bit = 1u << i;
            if ((cand & bit) && !(supp & bit)) { kept |= bit; supp |= mv[i]; }
        }
        s_keptmask = kept;
    }
    __syncthreads();

    // ---- Output (wave 0 only; det rows still in registers) ----
    if (tid < 64) {
        const unsigned kept = s_keptmask;
        const int K = __popc(kept);
        float* ob = out + (size_t)b * (TOPK * 8);
        if ((tid < NSEL) && ((kept >> tid) & 1u)) {
            const int r = __popc(kept & ((1u << tid) - 1u));
            float4* row = (float4*)(ob + r * 8);
            row[0] = make_float4(1.0f, score, cz, cy);
            row[1] = make_float4(cx, ez, ey, ex);
        }
        const int n4 = (TOPK - K) * 2;               // float4s of -1 fill
        float4* fb = (float4*)(ob + K * 8);
        const float4 neg = make_float4(-1.f, -1.f, -1.f, -1.f);
        for (int i = tid; i < n4; i += 64) fb[i] = neg;
    }
}

extern "C" void kernel_launch(void* const* d_in, const int* in_sizes, int n_in,
                              void* d_out, int out_size, void* d_ws, size_t ws_size,
                              hipStream_t stream) {
    (void)n_in; (void)out_size; (void)d_ws; (void)ws_size;
    const float* cls = (const float*)d_in[0];
    const float* shp = (const float*)d_in[1];
    const float* off = (const float*)d_in[2];
    float* out = (float*)d_out;
    const int B = in_sizes[0] / AA;   // 256
    detpost<<<B, BLOCK, 0, stream>>>(cls, shp, off, out);
}

// Round 4
// 114.371 us; speedup vs baseline: 1.0105x; 1.0007x over previous
//
#include <hip/hip_runtime.h>
#include <cstdint>

#define DD 24
#define AA 13824          // 24*24*24
#define NF4 3456          // AA/4
#define BLOCK 1024
#define TOPK 60           // output rows per batch (unchanged)
#define NSEL 20           // only the first NMS_TOPK=20 valid candidates can ever be kept:
                          // valid scores (>THRESH) are strictly greater than invalid ones,
                          // so top-20-by-value contains the whole cand set of the reference.
#define THRESH 0.15f
#define NMS_THR 0.05f
#define NBINS 4096
#define BUFCAP 2048

__device__ __forceinline__ unsigned skey(float f) {
    unsigned u = __float_as_uint(f);
    return (u & 0x80000000u) ? ~u : (u | 0x80000000u);
}

__global__ __launch_bounds__(BLOCK, 4) void detpost(
    const float* __restrict__ cls,
    const float* __restrict__ shp,
    const float* __restrict__ off,
    float* __restrict__ out)
{
    __shared__ int      s_hist[NBINS];
    __shared__ int      s_S[257];
    __shared__ int      s_wsum[4];
    __shared__ int      s_seg;
    __shared__ int      s_bt;
    __shared__ int      s_cnt;
    __shared__ float    s_bufv[BUFCAP];
    __shared__ int      s_bufi[BUFCAP];
    __shared__ float    s_topv[NSEL];
    __shared__ int      s_topi[NSEL];
    __shared__ float    s_lo[3][NSEL], s_hi[3][NSEL], s_vol[NSEL];
    __shared__ float    s_det[NSEL][8];      // 1, score, cz, cy, cx, ez, ey, ex
    __shared__ unsigned s_m[NSEL];           // 20-bit suppression masks
    __shared__ unsigned s_candmask, s_keptmask;

    const int b   = blockIdx.x;
    const int tid = threadIdx.x;

    for (int i = tid; i < NBINS; i += BLOCK) s_hist[i] = 0;
    if (tid == 0) { s_cnt = 0; s_seg = 0; s_S[256] = 0; }
    __syncthreads();

    // ---- Pass 1: load cls into registers + histogram of top-12-bit sortable keys
    const float4* cls4 = (const float4*)(cls + (size_t)b * AA);
    const bool has3 = (tid + 3072) < NF4;    // NF4 = 3456: threads 0..383
    float4 r0 = cls4[tid];
    float4 r1 = cls4[tid + 1024];
    float4 r2 = cls4[tid + 2048];
    float4 r3 = has3 ? cls4[tid + 3072] : make_float4(0.f, 0.f, 0.f, 0.f);

    atomicAdd(&s_hist[skey(r0.x) >> 20], 1);
    atomicAdd(&s_hist[skey(r0.y) >> 20], 1);
    atomicAdd(&s_hist[skey(r0.z) >> 20], 1);
    atomicAdd(&s_hist[skey(r0.w) >> 20], 1);
    atomicAdd(&s_hist[skey(r1.x) >> 20], 1);
    atomicAdd(&s_hist[skey(r1.y) >> 20], 1);
    atomicAdd(&s_hist[skey(r1.z) >> 20], 1);
    atomicAdd(&s_hist[skey(r1.w) >> 20], 1);
    atomicAdd(&s_hist[skey(r2.x) >> 20], 1);
    atomicAdd(&s_hist[skey(r2.y) >> 20], 1);
    atomicAdd(&s_hist[skey(r2.z) >> 20], 1);
    atomicAdd(&s_hist[skey(r2.w) >> 20], 1);
    if (has3) {
        atomicAdd(&s_hist[skey(r3.x) >> 20], 1);
        atomicAdd(&s_hist[skey(r3.y) >> 20], 1);
        atomicAdd(&s_hist[skey(r3.z) >> 20], 1);
        atomicAdd(&s_hist[skey(r3.w) >> 20], 1);
    }
    __syncthreads();

    // ---- Find pivot bin bt: smallest bin with count(bin >= bt) >= NSEL (waves 0-3)
    if (tid < 256) {
        int part = 0;
        #pragma unroll
        for (int i = 0; i < 16; ++i) part += s_hist[tid * 16 + i];
        const int lane = tid & 63, wv = tid >> 6;
        int x = part;
        #pragma unroll
        for (int d2 = 1; d2 < 64; d2 <<= 1) {
            int y = __shfl_up(x, d2, 64);
            if (lane >= d2) x += y;
        }
        if (lane == 63) s_wsum[wv] = x;
        s_S[tid] = part;                       // stash segment count
        s_bufv[tid] = __int_as_float(x);       // stash inclusive wave-scan
    }
    __syncthreads();
    if (tid < 256) {
        const int wv = tid >> 6;
        const int part = s_S[tid];
        const int x = __float_as_int(s_bufv[tid]);
        int offp = 0, tot = 0;
        #pragma unroll
        for (int wq = 0; wq < 4; ++wq) {
            int s = s_wsum[wq];
            tot += s;
            if (wq < wv) offp += s;
        }
        const int Pincl = x + offp;
        const int S = tot - Pincl + part;   // suffix sum over segments >= tid
        s_S[tid] = S;
        if (S >= NSEL) atomicMax(&s_seg, tid);
    }
    __syncthreads();
    if (tid == 0) {
        const int seg = s_seg;
        int acc = (seg < 255) ? s_S[seg + 1] : 0;
        int bt = seg * 16;
        for (int i = 15; i >= 0; --i) {
            int c = s_hist[seg * 16 + i];
            if (acc + c >= NSEL) { bt = seg * 16 + i; break; }
            acc += c;
        }
        s_bt = bt;
    }
    __syncthreads();
    const unsigned bt = (unsigned)s_bt;

    // ---- Pass 2: collect candidates from registers ----
    {
        const int b0 = 4 * tid, b1 = 4 * (tid + 1024), b2 = 4 * (tid + 2048), b3 = 4 * (tid + 3072);
        #define COLL(v, e) if ((skey(v) >> 20) >= bt) { \
            int pos = atomicAdd(&s_cnt, 1); \
            if (pos < BUFCAP) { s_bufv[pos] = (v); s_bufi[pos] = (e); } }
        COLL(r0.x, b0 + 0) COLL(r0.y, b0 + 1) COLL(r0.z, b0 + 2) COLL(r0.w, b0 + 3)
        COLL(r1.x, b1 + 0) COLL(r1.y, b1 + 1) COLL(r1.z, b1 + 2) COLL(r1.w, b1 + 3)
        COLL(r2.x, b2 + 0) COLL(r2.y, b2 + 1) COLL(r2.z, b2 + 2) COLL(r2.w, b2 + 3)
        if (has3) { COLL(r3.x, b3 + 0) COLL(r3.y, b3 + 1) COLL(r3.z, b3 + 2) COLL(r3.w, b3 + 3) }
        #undef COLL
    }
    __syncthreads();
    int C = s_cnt; if (C > BUFCAP) C = BUFCAP;

    // ---- Exact top-20 by rank counting (desc value, tie: lower index first) ----
    for (int j = tid; j < C; j += BLOCK) {
        const float vj = s_bufv[j];
        const int   ij = s_bufi[j];
        int r = 0;
        for (int k = 0; k < C; ++k) {
            const float vk = s_bufv[k];
            const int   ik = s_bufi[k];
            r += (int)((vk > vj) || (vk == vj && ik < ij));
        }
        if (r < NSEL) { s_topv[r] = vj; s_topi[r] = ij; }
    }
    __syncthreads();

    // ---- Decode boxes for the 20 finalists ----
    if (tid < NSEL) {
        s_m[tid] = 0u;
        const float v = s_topv[tid];
        const int   a = s_topi[tid];
        const float score = 1.0f / (1.0f + expf(-v));
        const int z  = a / (DD * DD);
        const int y  = (a / DD) % DD;
        const int xg = a % DD;
        const size_t base3 = (size_t)b * 3 * AA;
        const float o0 = off[base3 + 0 * AA + a];
        const float o1 = off[base3 + 1 * AA + a];
        const float o2 = off[base3 + 2 * AA + a];
        const float s0 = shp[base3 + 0 * AA + a];
        const float s1 = shp[base3 + 1 * AA + a];
        const float s2 = shp[base3 + 2 * AA + a];
        const float cz = ((float)z  + o0) * 4.0f;
        const float cy = ((float)y  + o1) * 4.0f;
        const float cx = ((float)xg + o2) * 4.0f;
        const float ez = 2.0f * s0, ey = 2.0f * s1, ex = 2.0f * s2;
        // mirror reference fp op order exactly
        s_lo[0][tid] = cz - ez * 0.5f;  s_hi[0][tid] = cz + ez * 0.5f;
        s_lo[1][tid] = cy - ey * 0.5f;  s_hi[1][tid] = cy + ey * 0.5f;
        s_lo[2][tid] = cx - ex * 0.5f;  s_hi[2][tid] = cx + ex * 0.5f;
        s_vol[tid]   = (ez * ey) * ex;
        s_det[tid][0] = 1.0f;  s_det[tid][1] = score;
        s_det[tid][2] = cz;    s_det[tid][3] = cy;   s_det[tid][4] = cx;
        s_det[tid][5] = ez;    s_det[tid][6] = ey;   s_det[tid][7] = ex;
    }
    __syncthreads();

    // ---- Parallel IoU suppression masks (400 pairs) + candidate mask ----
    // All valid (>THRESH) entries rank ahead of all invalid ones in value order,
    // so every valid entry in the top-20 is a cand (rank<20 automatic).
    if (tid == BLOCK - 1) {
        unsigned cm = 0u;
        for (int i = 0; i < NSEL; ++i)
            if (s_det[i][1] > THRESH) cm |= (1u << i);
        s_candmask = cm;
    }
    if (tid < NSEL * NSEL) {
        const int i = tid / NSEL, j = tid - i * NSEL;
        if (i != j) {
            const float tz = fmaxf(fminf(s_hi[0][i], s_hi[0][j]) - fmaxf(s_lo[0][i], s_lo[0][j]), 0.0f);
            const float ty = fmaxf(fminf(s_hi[1][i], s_hi[1][j]) - fmaxf(s_lo[1][i], s_lo[1][j]), 0.0f);
            const float tx = fmaxf(fminf(s_hi[2][i], s_hi[2][j]) - fmaxf(s_lo[2][i], s_lo[2][j]), 0.0f);
            const float inter = (tz * ty) * tx;
            const float uni = (s_vol[i] + s_vol[j]) - inter;
            const float iou = inter / fmaxf(uni, 1e-8f);
            if (iou > NMS_THR) atomicOr(&s_m[i], 1u << j);
        }
    }
    __syncthreads();

    // ---- Serial greedy NMS (pure bit ops, thread 0) ----
    if (tid == 0) {
        unsigned supp = 0u, kept = 0u;
        const unsigned cm = s_candmask;
        for (int i = 0; i < NSEL; ++i) {
            const unsigned bit = 1u << i;
            if ((cm & bit) && !(supp & bit)) {
                kept |= bit;
                supp |= s_m[i];
            }
        }
        s_keptmask = kept;
    }
    __syncthreads();

    // ---- Output ----
    const unsigned kept = s_keptmask;
    const int K = __popc(kept);
    float* ob = out + (size_t)b * (TOPK * 8);
    if (tid < NSEL && ((kept >> tid) & 1u)) {
        const int r = __popc(kept & ((1u << tid) - 1u));
        float* row = ob + r * 8;
        #pragma unroll
        for (int q = 0; q < 8; ++q) row[q] = s_det[tid][q];
    }
    const int fill = (TOPK - K) * 8;
    for (int idx = tid; idx < fill; idx += BLOCK) ob[K * 8 + idx] = -1.0f;
}

extern "C" void kernel_launch(void* const* d_in, const int* in_sizes, int n_in,
                              void* d_out, int out_size, void* d_ws, size_t ws_size,
                              hipStream_t stream) {
    (void)n_in; (void)out_size; (void)d_ws; (void)ws_size;
    const float* cls = (const float*)d_in[0];
    const float* shp = (const float*)d_in[1];
    const float* off = (const float*)d_in[2];
    float* out = (float*)d_out;
    const int B = in_sizes[0] / AA;   // 256
    detpost<<<B, BLOCK, 0, stream>>>(cls, shp, off, out);
}